// Round 8
// baseline (55.133 us; speedup 1.0000x reference)
//
#include <hip/hip_runtime.h>

// Problem constants (match reference)
#define B_  16
#define P_  32
#define L_  512
#define M_  32
#define LE_ 2048

#define MSPLIT 8                 // m's per block
#define MC     (M_ / MSPLIT)     // 4 m-groups

// One block = (b, p, group of 8 m's). Params packed as float4 (mu,al,be,0)
// per (m,j) in LDS -> ONE ds_read_b128 per (m,query) gather instead of three
// conflicting ds_read_b32 (round-7 was LDS-pipe-bound: 1.39M bank conflicts).
// Staging: coalesced global float4 loads + register transpose -> packed
// ds_write_b128 (conflict-free). Numerics identical to the passing round-6
// kernel: qn = q * fl32_CR(1/nc), side='left' lower_bound + end-correction,
// dt = qn - t_last, __expf, scale by inv_nc.
__global__ __launch_bounds__(256, 2) void hawkes_intensity_kernel(
    const float* __restrict__ q,      // [B,P,LE]
    const float* __restrict__ ev,     // [B,P,L]
    const float* __restrict__ mu,     // [B,M,P,L]
    const float* __restrict__ alpha,  // [B,M,P,L]
    const float* __restrict__ beta,   // [B,M,P,L]
    const float* __restrict__ nc,     // [B]
    float* __restrict__ out)          // [B,M,P,LE]
{
    __shared__ float  sev[L_];                 // 2 KB
    __shared__ float4 spar[MSPLIT][L_];        // 64 KB packed (mu,al,be,0)

    const int bid = blockIdx.x;
    const int mc  = bid & (MC - 1);            // m-group (fastest)
    const int row = bid >> 2;                  // b*P_ + p
    const int b   = row / P_;
    const int p   = row % P_;
    const int m0  = mc * MSPLIT;
    const int tid = threadIdx.x;

    // Stage event row (512 floats)
    const float* evrow = ev + (size_t)row * L_;
    sev[tid]       = evrow[tid];
    sev[tid + 256] = evrow[tid + 256];

    // Stage params packed: 8 m-rows x 512 entries; 1024 float4-triples total.
    const size_t pbase   = (((size_t)b * M_ + m0) * P_ + p) * L_;
    const size_t mstride = (size_t)P_ * L_;    // floats between m rows
    #pragma unroll
    for (int i = 0; i < 4; ++i) {
        const int fidx = tid + 256 * i;        // 0..1023
        const int ml   = fidx >> 7;            // /128
        const int l4   = (fidx & 127) << 2;    // float offset in row
        const size_t g = pbase + (size_t)ml * mstride + l4;
        const float4 mv = *(const float4*)(mu    + g);
        const float4 av = *(const float4*)(alpha + g);
        const float4 bv = *(const float4*)(beta  + g);
        spar[ml][l4 + 0] = make_float4(mv.x, av.x, bv.x, 0.0f);
        spar[ml][l4 + 1] = make_float4(mv.y, av.y, bv.y, 0.0f);
        spar[ml][l4 + 2] = make_float4(mv.z, av.z, bv.z, 0.0f);
        spar[ml][l4 + 3] = make_float4(mv.w, av.w, bv.w, 0.0f);
    }
    __syncthreads();

    const float ncv    = nc[b];
    const float inv_nc = (float)(1.0 / (double)ncv);  // CR f32 reciprocal
    const float* qrow  = q + (size_t)row * LE_;

    #pragma unroll
    for (int pass = 0; pass < 2; ++pass) {
        const int le0 = 1024 * pass + 4 * tid;
        const float4 qv = *(const float4*)(qrow + le0);

        int   idx[4];
        float dt[4];
        #pragma unroll
        for (int i = 0; i < 4; ++i) {
            const float qn = ((const float*)&qv)[i] * inv_nc;
            int pos = 0;
            #pragma unroll
            for (int half = 256; half >= 1; half >>= 1) {
                const int cand = pos + half;
                pos = (sev[cand - 1] < qn) ? cand : pos;
            }
            pos += (sev[pos] < qn) ? 1 : 0;    // extend range to 512
            const int last = pos - 1;
            idx[i] = (last < 0) ? 0 : last;
            const float tl = (last < 0) ? 0.0f : sev[idx[i]];
            dt[i] = qn - tl;
        }

        const size_t obase = (((size_t)b * M_ + m0) * P_ + p) * LE_ + le0;
        #pragma unroll
        for (int m = 0; m < MSPLIT; ++m) {
            float4 o;
            #pragma unroll
            for (int i = 0; i < 4; ++i) {
                const float4 pv  = spar[m][idx[i]];
                const float  mul = pv.x;
                const float  al  = pv.y;
                const float  be  = pv.z;
                ((float*)&o)[i] = (mul + (al - mul) * __expf(-be * dt[i])) * inv_nc;
            }
            *(float4*)(out + obase + (size_t)m * ((size_t)P_ * LE_)) = o;
        }
    }
}

extern "C" void kernel_launch(void* const* d_in, const int* in_sizes, int n_in,
                              void* d_out, int out_size, void* d_ws, size_t ws_size,
                              hipStream_t stream) {
    const float* q     = (const float*)d_in[0];  // query_times [B,P,LE]
    const float* ev    = (const float*)d_in[1];  // event_times [B,P,L]
    const float* mu    = (const float*)d_in[2];  // [B,M,P,L]
    const float* alpha = (const float*)d_in[3];  // [B,M,P,L]
    const float* beta  = (const float*)d_in[4];  // [B,M,P,L]
    const float* nc    = (const float*)d_in[5];  // [B]
    float* out = (float*)d_out;                  // [B,M,P,LE]

    dim3 grid(B_ * P_ * MC);                     // 2048 blocks
    dim3 block(256);
    hipLaunchKernelGGL(hawkes_intensity_kernel, grid, block, 0, stream,
                       q, ev, mu, alpha, beta, nc, out);
}

// Round 9
// 50.630 us; speedup vs baseline: 1.0889x; 1.0889x over previous
//
#include <hip/hip_runtime.h>

// Problem constants (match reference)
#define B_  16
#define P_  32
#define L_  512
#define M_  32
#define LE_ 2048

#define MSPLIT 8                 // m's per apply-block
#define MC     (M_ / MSPLIT)     // 4 m-groups

// Numerics (validated round 6/7): qn = q * fl32_CR(1/nc); side='left'
// lower_bound with end-correction; dt = qn - t_last; __expf; scale inv_nc.

// ---------------- Kernel 1: search (idx, dt) once per (b,p) row ----------
__global__ __launch_bounds__(256) void hawkes_search_kernel(
    const float* __restrict__ q,      // [B,P,LE]
    const float* __restrict__ ev,     // [B,P,L]
    const float* __restrict__ nc,     // [B]
    float2* __restrict__ wsp)         // [B*P, LE] packed (idx_bits, dt)
{
    __shared__ float sev[L_];
    const int row = blockIdx.x;            // b*P_ + p
    const int b   = row / P_;
    const int tid = threadIdx.x;

    const float* evrow = ev + (size_t)row * L_;
    sev[tid]       = evrow[tid];
    sev[tid + 256] = evrow[tid + 256];
    __syncthreads();

    const float inv_nc = (float)(1.0 / (double)nc[b]);  // CR f32 reciprocal
    const float* qrow  = q + (size_t)row * LE_;
    float2* wrow = wsp + (size_t)row * LE_;

    #pragma unroll
    for (int pass = 0; pass < 2; ++pass) {
        const int le0 = 1024 * pass + 4 * tid;
        const float4 qv = *(const float4*)(qrow + le0);
        float2 o[4];
        #pragma unroll
        for (int i = 0; i < 4; ++i) {
            const float qn = ((const float*)&qv)[i] * inv_nc;
            int pos = 0;
            #pragma unroll
            for (int half = 256; half >= 1; half >>= 1) {
                const int cand = pos + half;
                pos = (sev[cand - 1] < qn) ? cand : pos;
            }
            pos += (sev[pos] < qn) ? 1 : 0;     // extend range to 512
            const int   last = pos - 1;
            const int   idx  = (last < 0) ? 0 : last;
            const float tl   = (last < 0) ? 0.0f : sev[idx];
            o[i].x = __int_as_float(idx);       // raw bits through memory
            o[i].y = qn - tl;
        }
        *(float4*)(wrow + le0)     = make_float4(o[0].x, o[0].y, o[1].x, o[1].y);
        *(float4*)(wrow + le0 + 2) = make_float4(o[2].x, o[2].y, o[3].x, o[3].y);
    }
}

// ---------------- Kernel 2: gather params + evaluate + store -------------
__global__ __launch_bounds__(512) void hawkes_apply_kernel(
    const float* __restrict__ mu,     // [B,M,P,L]
    const float* __restrict__ alpha,  // [B,M,P,L]
    const float* __restrict__ beta,   // [B,M,P,L]
    const float* __restrict__ nc,     // [B]
    const float2* __restrict__ wsp,   // [B*P, LE]
    float* __restrict__ out)          // [B,M,P,LE]
{
    __shared__ float smu[MSPLIT][L_];
    __shared__ float sal[MSPLIT][L_];
    __shared__ float sbe[MSPLIT][L_];

    const int bid = blockIdx.x;
    const int mc  = bid & (MC - 1);          // m-group (fastest)
    const int row = bid >> 2;                // b*P_ + p
    const int b   = row / P_;
    const int p   = row % P_;
    const int m0  = mc * MSPLIT;
    const int tid = threadIdx.x;             // 0..511

    // Stage params: 3 arrays x 8 rows x 512 floats = 3072 float4s; 6/thread.
    const size_t pbase   = (((size_t)b * M_ + m0) * P_ + p) * L_;
    const size_t mstride = (size_t)P_ * L_;
    #pragma unroll
    for (int i = 0; i < 2; ++i) {
        const int fidx = tid + 512 * i;      // 0..1023
        const int ml   = fidx >> 7;          // /128
        const int l4   = (fidx & 127) << 2;  // float offset in row
        const size_t g = pbase + (size_t)ml * mstride + l4;
        *(float4*)&smu[ml][l4] = *(const float4*)(mu    + g);
        *(float4*)&sal[ml][l4] = *(const float4*)(alpha + g);
        *(float4*)&sbe[ml][l4] = *(const float4*)(beta  + g);
    }
    __syncthreads();

    const float inv_nc = (float)(1.0 / (double)nc[b]);
    const float2* wrow = wsp + (size_t)row * LE_;

    const int le0 = 4 * tid;                 // each thread: 4 queries
    const float4 w0 = *(const float4*)(wrow + le0);
    const float4 w1 = *(const float4*)(wrow + le0 + 2);
    const int   idx[4] = { __float_as_int(w0.x), __float_as_int(w0.z),
                           __float_as_int(w1.x), __float_as_int(w1.z) };
    const float dt[4]  = { w0.y, w0.w, w1.y, w1.w };

    const size_t obase = (((size_t)b * M_ + m0) * P_ + p) * LE_ + le0;
    #pragma unroll
    for (int m = 0; m < MSPLIT; ++m) {
        float4 o;
        #pragma unroll
        for (int i = 0; i < 4; ++i) {
            const float mul = smu[m][idx[i]];
            const float al  = sal[m][idx[i]];
            const float be  = sbe[m][idx[i]];
            ((float*)&o)[i] = (mul + (al - mul) * __expf(-be * dt[i])) * inv_nc;
        }
        *(float4*)(out + obase + (size_t)m * ((size_t)P_ * LE_)) = o;
    }
}

// ---------------- Fallback: round-7 fused kernel (if ws too small) -------
__global__ __launch_bounds__(256) void hawkes_fused_kernel(
    const float* __restrict__ q, const float* __restrict__ ev,
    const float* __restrict__ mu, const float* __restrict__ alpha,
    const float* __restrict__ beta, const float* __restrict__ nc,
    float* __restrict__ out)
{
    __shared__ float sev[L_];
    __shared__ float smu[MSPLIT][L_];
    __shared__ float sal[MSPLIT][L_];
    __shared__ float sbe[MSPLIT][L_];

    const int bid = blockIdx.x;
    const int mc  = bid & (MC - 1);
    const int row = bid >> 2;
    const int b   = row / P_;
    const int p   = row % P_;
    const int m0  = mc * MSPLIT;
    const int tid = threadIdx.x;

    const float* evrow = ev + (size_t)row * L_;
    sev[tid]       = evrow[tid];
    sev[tid + 256] = evrow[tid + 256];

    const size_t pbase   = (((size_t)b * M_ + m0) * P_ + p) * L_;
    const size_t mstride = (size_t)P_ * L_;
    #pragma unroll
    for (int i = 0; i < 4; ++i) {
        const int fidx = tid + 256 * i;
        const int ml   = fidx >> 7;
        const int l4   = (fidx & 127) << 2;
        const size_t g = pbase + (size_t)ml * mstride + l4;
        *(float4*)&smu[ml][l4] = *(const float4*)(mu    + g);
        *(float4*)&sal[ml][l4] = *(const float4*)(alpha + g);
        *(float4*)&sbe[ml][l4] = *(const float4*)(beta  + g);
    }
    __syncthreads();

    const float inv_nc = (float)(1.0 / (double)nc[b]);
    const float* qrow  = q + (size_t)row * LE_;

    #pragma unroll
    for (int pass = 0; pass < 2; ++pass) {
        const int le0 = 1024 * pass + 4 * tid;
        const float4 qv = *(const float4*)(qrow + le0);
        int idx[4]; float dt[4];
        #pragma unroll
        for (int i = 0; i < 4; ++i) {
            const float qn = ((const float*)&qv)[i] * inv_nc;
            int pos = 0;
            #pragma unroll
            for (int half = 256; half >= 1; half >>= 1) {
                const int cand = pos + half;
                pos = (sev[cand - 1] < qn) ? cand : pos;
            }
            pos += (sev[pos] < qn) ? 1 : 0;
            const int last = pos - 1;
            idx[i] = (last < 0) ? 0 : last;
            const float tl = (last < 0) ? 0.0f : sev[idx[i]];
            dt[i] = qn - tl;
        }
        const size_t obase = (((size_t)b * M_ + m0) * P_ + p) * LE_ + le0;
        #pragma unroll
        for (int m = 0; m < MSPLIT; ++m) {
            float4 o;
            #pragma unroll
            for (int i = 0; i < 4; ++i) {
                const float mul = smu[m][idx[i]];
                const float al  = sal[m][idx[i]];
                const float be  = sbe[m][idx[i]];
                ((float*)&o)[i] = (mul + (al - mul) * __expf(-be * dt[i])) * inv_nc;
            }
            *(float4*)(out + obase + (size_t)m * ((size_t)P_ * LE_)) = o;
        }
    }
}

extern "C" void kernel_launch(void* const* d_in, const int* in_sizes, int n_in,
                              void* d_out, int out_size, void* d_ws, size_t ws_size,
                              hipStream_t stream) {
    const float* q     = (const float*)d_in[0];  // query_times [B,P,LE]
    const float* ev    = (const float*)d_in[1];  // event_times [B,P,L]
    const float* mu    = (const float*)d_in[2];  // [B,M,P,L]
    const float* alpha = (const float*)d_in[3];  // [B,M,P,L]
    const float* beta  = (const float*)d_in[4];  // [B,M,P,L]
    const float* nc    = (const float*)d_in[5];  // [B]
    float* out = (float*)d_out;                  // [B,M,P,LE]

    const size_t ws_needed = (size_t)B_ * P_ * LE_ * sizeof(float2); // 8 MB
    if (ws_size >= ws_needed) {
        float2* wsp = (float2*)d_ws;
        hipLaunchKernelGGL(hawkes_search_kernel, dim3(B_ * P_), dim3(256), 0,
                           stream, q, ev, nc, wsp);
        hipLaunchKernelGGL(hawkes_apply_kernel, dim3(B_ * P_ * MC), dim3(512),
                           0, stream, mu, alpha, beta, nc, wsp, out);
    } else {
        hipLaunchKernelGGL(hawkes_fused_kernel, dim3(B_ * P_ * MC), dim3(256),
                           0, stream, q, ev, mu, alpha, beta, nc, out);
    }
}